// Round 1
// baseline (352.113 us; speedup 1.0000x reference)
//
#include <hip/hip_runtime.h>
#include <hip/hip_bf16.h>

namespace {

constexpr int T = 4, H = 128, W = 128, C = 256, HD = 8, K = 9, F = 32;
constexpr int M = T * H * W;  // 65536

__device__ __forceinline__ unsigned short f2bf(float f) {
  unsigned u = __float_as_uint(f);
  unsigned r = (u + 0x7fffu + ((u >> 16) & 1u)) >> 16;
  return (unsigned short)r;
}

__device__ __forceinline__ float bf2f(unsigned short u) {
  return __uint_as_float(((unsigned)u) << 16);
}

// Kernel 1: v[m][n] = sum_k x[m][k] * vw[n][k], stored bf16.
// Tiles: BM=64, BN=64, BK=16; 256 threads; 4x4 micro-tile.
__global__ __launch_bounds__(256) void vproj_kernel(
    const float* __restrict__ x, const float* __restrict__ vw,
    unsigned short* __restrict__ v) {
  __shared__ float As[64][17];
  __shared__ float Bs[64][17];
  const int m0 = blockIdx.x * 64;
  const int n0 = blockIdx.y * 64;
  const int tid = threadIdx.x;
  const int lrow = tid >> 2;
  const int lcg = (tid & 3) * 4;
  const int tx = tid & 15, ty = tid >> 4;
  float acc[4][4] = {};
  for (int k0 = 0; k0 < C; k0 += 16) {
    const float4 a4 = *(const float4*)(x + (size_t)(m0 + lrow) * C + k0 + lcg);
    const float4 b4 = *(const float4*)(vw + (size_t)(n0 + lrow) * C + k0 + lcg);
    __syncthreads();
    As[lrow][lcg + 0] = a4.x; As[lrow][lcg + 1] = a4.y;
    As[lrow][lcg + 2] = a4.z; As[lrow][lcg + 3] = a4.w;
    Bs[lrow][lcg + 0] = b4.x; Bs[lrow][lcg + 1] = b4.y;
    Bs[lrow][lcg + 2] = b4.z; Bs[lrow][lcg + 3] = b4.w;
    __syncthreads();
#pragma unroll
    for (int kk = 0; kk < 16; ++kk) {
      float a[4], b[4];
#pragma unroll
      for (int i = 0; i < 4; ++i) a[i] = As[ty * 4 + i][kk];
#pragma unroll
      for (int j = 0; j < 4; ++j) b[j] = Bs[tx * 4 + j][kk];
#pragma unroll
      for (int i = 0; i < 4; ++i)
#pragma unroll
        for (int j = 0; j < 4; ++j) acc[i][j] += a[i] * b[j];
    }
  }
#pragma unroll
  for (int i = 0; i < 4; ++i) {
    ushort4 o;
    o.x = f2bf(acc[i][0]);
    o.y = f2bf(acc[i][1]);
    o.z = f2bf(acc[i][2]);
    o.w = f2bf(acc[i][3]);
    *(ushort4*)(v + (size_t)(m0 + ty * 4 + i) * C + n0 + tx * 4) = o;
  }
}

// Kernel 2: fused gather + attn-weighted sum (into LDS) + proj GEMM + bias.
// Block = 32 positions (8h x 4w tile at fixed t). 256 threads.
__global__ __launch_bounds__(256) void agg_proj_kernel(
    const unsigned short* __restrict__ v, const float* __restrict__ attn,
    const int* __restrict__ flows, const float* __restrict__ proj_w,
    const float* __restrict__ proj_b, float* __restrict__ out) {
  __shared__ float Agg[32][C];   // 32 KB
  __shared__ float Bs[32][C];    // 32 KB (k-major x n)
  const int bid = blockIdx.x;
  const int t = bid >> 9;
  const int h0 = ((bid >> 5) & 15) * 8;
  const int w0 = (bid & 31) * 4;
  const int tid = threadIdx.x;

  // ---- Phase 1: gather + weighted sum -> Agg[pos][c] ----
  const int g = tid >> 3;       // group 0..31
  const int f4 = (tid & 7) * 4; // f offset, 4 elems per lane
#pragma unroll
  for (int r = 0; r < 8; ++r) {
    const int pi = r * 32 + g;        // (pos,head) pair 0..255
    const int pos = pi >> 3;
    const int head = pi & 7;
    const int h = h0 + (pos >> 2);
    const int w = w0 + (pos & 3);
    const int base = (((head * T + t) * H + h) * W + w) * K;
    const int fbase = base * 3;
    float4 acc = {0.f, 0.f, 0.f, 0.f};
#pragma unroll
    for (int k = 0; k < K; ++k) {
      const int dt = flows[fbase + k * 3 + 0];
      const int dh = flows[fbase + k * 3 + 1];
      const int dw = flows[fbase + k * 3 + 2];
      const float aw = attn[base + k];
      const int tt = min(max(t + dt, 0), T - 1);
      const int hh = min(max(h + dh, 0), H - 1);
      const int ww = min(max(w + dw, 0), W - 1);
      const int mm = (tt * H + hh) * W + ww;
      const ushort4 r4 =
          *(const ushort4*)(v + (size_t)mm * C + head * F + f4);
      acc.x += aw * bf2f(r4.x);
      acc.y += aw * bf2f(r4.y);
      acc.z += aw * bf2f(r4.z);
      acc.w += aw * bf2f(r4.w);
    }
    *(float4*)&Agg[pos][head * F + f4] = acc;
  }
  __syncthreads();

  // ---- Phase 2: out[pos][n] = sum_k Agg[pos][k] * proj_w[n][k] + b[n] ----
  const int tx = tid & 31;  // n-group: cols tx*8..tx*8+7
  const int ty = tid >> 5;  // row-group: rows ty*4..ty*4+3
  float acc2[4][8];
  {
    const float4 b0 = *(const float4*)(proj_b + tx * 8);
    const float4 b1 = *(const float4*)(proj_b + tx * 8 + 4);
#pragma unroll
    for (int i = 0; i < 4; ++i) {
      acc2[i][0] = b0.x; acc2[i][1] = b0.y; acc2[i][2] = b0.z; acc2[i][3] = b0.w;
      acc2[i][4] = b1.x; acc2[i][5] = b1.y; acc2[i][6] = b1.z; acc2[i][7] = b1.w;
    }
  }
  for (int k0 = 0; k0 < C; k0 += 32) {
    // stage proj_w[n][k0..k0+32) transposed into Bs[kk][n]
#pragma unroll
    for (int i = 0; i < 8; ++i) {
      const float4 w4 = *(const float4*)(proj_w + (size_t)tid * C + k0 + i * 4);
      Bs[i * 4 + 0][tid] = w4.x;
      Bs[i * 4 + 1][tid] = w4.y;
      Bs[i * 4 + 2][tid] = w4.z;
      Bs[i * 4 + 3][tid] = w4.w;
    }
    __syncthreads();
#pragma unroll 4
    for (int kk = 0; kk < 32; ++kk) {
      const float4 bb0 = *(const float4*)&Bs[kk][tx * 8];
      const float4 bb1 = *(const float4*)&Bs[kk][tx * 8 + 4];
      float a[4];
#pragma unroll
      for (int i = 0; i < 4; ++i) a[i] = Agg[ty * 4 + i][k0 + kk];
#pragma unroll
      for (int i = 0; i < 4; ++i) {
        acc2[i][0] += a[i] * bb0.x;
        acc2[i][1] += a[i] * bb0.y;
        acc2[i][2] += a[i] * bb0.z;
        acc2[i][3] += a[i] * bb0.w;
        acc2[i][4] += a[i] * bb1.x;
        acc2[i][5] += a[i] * bb1.y;
        acc2[i][6] += a[i] * bb1.z;
        acc2[i][7] += a[i] * bb1.w;
      }
    }
    __syncthreads();
  }
#pragma unroll
  for (int i = 0; i < 4; ++i) {
    const int pos = ty * 4 + i;
    const int h = h0 + (pos >> 2);
    const int w = w0 + (pos & 3);
    const int m = (t * H + h) * W + w;
    float4 o0, o1;
    o0.x = acc2[i][0]; o0.y = acc2[i][1]; o0.z = acc2[i][2]; o0.w = acc2[i][3];
    o1.x = acc2[i][4]; o1.y = acc2[i][5]; o1.z = acc2[i][6]; o1.w = acc2[i][7];
    *(float4*)(out + (size_t)m * C + tx * 8) = o0;
    *(float4*)(out + (size_t)m * C + tx * 8 + 4) = o1;
  }
}

}  // namespace

extern "C" void kernel_launch(void* const* d_in, const int* in_sizes, int n_in,
                              void* d_out, int out_size, void* d_ws,
                              size_t ws_size, hipStream_t stream) {
  const float* x = (const float*)d_in[0];
  const float* attn = (const float*)d_in[1];
  const int* flows = (const int*)d_in[2];
  const float* v_w = (const float*)d_in[3];
  const float* proj_w = (const float*)d_in[4];
  const float* proj_b = (const float*)d_in[5];
  float* out = (float*)d_out;
  unsigned short* v = (unsigned short*)d_ws;  // M*C bf16 = 32 MB

  dim3 g1(M / 64, C / 64);
  vproj_kernel<<<g1, 256, 0, stream>>>(x, v_w, v);

  const int nblk = (T * (H / 8) * (W / 4));  // 2048
  agg_proj_kernel<<<nblk, 256, 0, stream>>>(v, attn, flows, proj_w, proj_b,
                                            out);
}

// Round 2
// 114.650 us; speedup vs baseline: 3.0712x; 3.0712x over previous
//
#include <hip/hip_runtime.h>
#include <hip/hip_bf16.h>

namespace {

constexpr int T = 4, H = 128, W = 128, C = 256, HD = 8, K = 9, F = 32;
constexpr int M = T * H * W;  // 65536

typedef __attribute__((ext_vector_type(8))) short short8v;   // 8 bf16 (4 VGPR)
typedef __attribute__((ext_vector_type(4))) float f32x4;     // MFMA acc

__device__ __forceinline__ unsigned short f2bf(float f) {
  unsigned u = __float_as_uint(f);
  unsigned r = (u + 0x7fffu + ((u >> 16) & 1u)) >> 16;
  return (unsigned short)r;
}

__device__ __forceinline__ float bf2f(unsigned short u) {
  return __uint_as_float(((unsigned)u) << 16);
}

// ---------------------------------------------------------------------------
// Templated MFMA GEMM: Cout[m][n] = sum_k A[m][k] * B[n][k]  (+ bias[n])
//   A: fp32 or bf16 (A_BF16), row-major [M][256]
//   B: fp32 row-major [N][256] (converted to bf16 during staging)
//   Cout: bf16 (OUT_F32=false) or fp32 (+bias) (OUT_F32=true)
// Block: 256 thr (4 waves, 2x2), tile 128x128, BK=32, LDS padded to 40 elems
// (80B row stride -> near-uniform bank use for ds_read_b128 fragments).
// ---------------------------------------------------------------------------
template <bool A_BF16, bool OUT_F32>
__global__ __launch_bounds__(256) void mfma_gemm(
    const void* __restrict__ Aptr, const float* __restrict__ Bw,
    void* __restrict__ Cptr, const float* __restrict__ bias) {
  __shared__ unsigned short As[128][40];
  __shared__ unsigned short Bs[128][40];
  const int m0 = blockIdx.x * 128;
  const int n0 = blockIdx.y * 128;
  const int t = threadIdx.x;
  const int lane = t & 63;
  const int wid = t >> 6;
  const int wm = wid >> 1, wn = wid & 1;
  const int fr = lane & 15;   // frag row/col within 16
  const int kg = lane >> 4;   // k-group 0..3

  f32x4 acc[4][4];
#pragma unroll
  for (int ni = 0; ni < 4; ++ni) {
    float b = 0.f;
    if (OUT_F32) b = bias[n0 + wn * 64 + ni * 16 + fr];
#pragma unroll
    for (int mi = 0; mi < 4; ++mi) {
      acc[mi][ni][0] = b; acc[mi][ni][1] = b;
      acc[mi][ni][2] = b; acc[mi][ni][3] = b;
    }
  }

  for (int k0 = 0; k0 < C; k0 += 32) {
    __syncthreads();  // protect LDS from previous iteration's readers
    // ---- stage A tile (128 x 32) as bf16 ----
    if (A_BF16) {
      const unsigned short* Ab = (const unsigned short*)Aptr;
#pragma unroll
      for (int i = 0; i < 2; ++i) {
        const int flat = t + i * 256;          // 0..511
        const int row = flat >> 2, kc = (flat & 3) * 8;
        *(short8v*)&As[row][kc] =
            *(const short8v*)(Ab + (size_t)(m0 + row) * C + k0 + kc);
      }
    } else {
      const float* Af = (const float*)Aptr;
#pragma unroll
      for (int i = 0; i < 4; ++i) {
        const int flat = t + i * 256;          // 0..1023
        const int row = flat >> 3, kc = (flat & 7) * 4;
        const float4 v4 = *(const float4*)(Af + (size_t)(m0 + row) * C + k0 + kc);
        ushort4 o;
        o.x = f2bf(v4.x); o.y = f2bf(v4.y); o.z = f2bf(v4.z); o.w = f2bf(v4.w);
        *(ushort4*)&As[row][kc] = o;
      }
    }
    // ---- stage B tile (128 x 32) fp32 -> bf16 ----
#pragma unroll
    for (int i = 0; i < 4; ++i) {
      const int flat = t + i * 256;
      const int row = flat >> 3, kc = (flat & 7) * 4;
      const float4 v4 = *(const float4*)(Bw + (size_t)(n0 + row) * C + k0 + kc);
      ushort4 o;
      o.x = f2bf(v4.x); o.y = f2bf(v4.y); o.z = f2bf(v4.z); o.w = f2bf(v4.w);
      *(ushort4*)&Bs[row][kc] = o;
    }
    __syncthreads();
    // ---- fragments + MFMA ----
    short8v af[4], bfv[4];
#pragma unroll
    for (int mi = 0; mi < 4; ++mi)
      af[mi] = *(const short8v*)&As[wm * 64 + mi * 16 + fr][kg * 8];
#pragma unroll
    for (int ni = 0; ni < 4; ++ni)
      bfv[ni] = *(const short8v*)&Bs[wn * 64 + ni * 16 + fr][kg * 8];
#pragma unroll
    for (int mi = 0; mi < 4; ++mi)
#pragma unroll
      for (int ni = 0; ni < 4; ++ni)
        acc[mi][ni] = __builtin_amdgcn_mfma_f32_16x16x32_bf16(
            af[mi], bfv[ni], acc[mi][ni], 0, 0, 0);
  }

  // ---- epilogue: D layout col = lane&15, row = (lane>>4)*4 + reg ----
#pragma unroll
  for (int mi = 0; mi < 4; ++mi) {
#pragma unroll
    for (int ni = 0; ni < 4; ++ni) {
      const int gcol = n0 + wn * 64 + ni * 16 + fr;
#pragma unroll
      for (int r = 0; r < 4; ++r) {
        const int grow = m0 + wm * 64 + mi * 16 + kg * 4 + r;
        if (OUT_F32) {
          ((float*)Cptr)[(size_t)grow * C + gcol] = acc[mi][ni][r];
        } else {
          ((unsigned short*)Cptr)[(size_t)grow * C + gcol] = f2bf(acc[mi][ni][r]);
        }
      }
    }
  }
}

// ---------------------------------------------------------------------------
// Gather kernel (split path): zero LDS, high occupancy.
// Thread = (pair, fq): pair = head*M + m (head-major), fq = 8-elem f chunk.
// ---------------------------------------------------------------------------
__global__ __launch_bounds__(256) void gather_kernel(
    const unsigned short* __restrict__ v, const float* __restrict__ attn,
    const int* __restrict__ flows, unsigned short* __restrict__ agg) {
  const int g = blockIdx.x * 256 + threadIdx.x;
  const int pair = g >> 2;
  const int fq = g & 3;
  const int head = pair >> 16;
  const int m = pair & 65535;
  const int t = m >> 14;
  const int h = (m >> 7) & 127;
  const int w = m & 127;
  const int base = pair * K;
  const int fbase = base * 3;
  const int foff = head * F + fq * 8;

  float facc[8] = {0.f, 0.f, 0.f, 0.f, 0.f, 0.f, 0.f, 0.f};
#pragma unroll
  for (int k = 0; k < K; ++k) {
    const int dt = flows[fbase + k * 3 + 0];
    const int dh = flows[fbase + k * 3 + 1];
    const int dw = flows[fbase + k * 3 + 2];
    const float aw = attn[base + k];
    const int tt = min(max(t + dt, 0), T - 1);
    const int hh = min(max(h + dh, 0), H - 1);
    const int ww = min(max(w + dw, 0), W - 1);
    const int mm = (tt << 14) | (hh << 7) | ww;
    const short8v r8 = *(const short8v*)(v + (size_t)mm * C + foff);
#pragma unroll
    for (int j = 0; j < 8; ++j)
      facc[j] += aw * bf2f((unsigned short)r8[j]);
  }
  short8v o;
#pragma unroll
  for (int j = 0; j < 8; ++j) o[j] = (short)f2bf(facc[j]);
  *(short8v*)(agg + (size_t)m * C + foff) = o;
}

// ---------------------------------------------------------------------------
// Fallback (ws too small): round-1 fused gather + fp32 proj GEMM. Proven.
// ---------------------------------------------------------------------------
__global__ __launch_bounds__(256) void agg_proj_kernel(
    const unsigned short* __restrict__ v, const float* __restrict__ attn,
    const int* __restrict__ flows, const float* __restrict__ proj_w,
    const float* __restrict__ proj_b, float* __restrict__ out) {
  __shared__ float Agg[32][C];
  __shared__ float Bs[32][C];
  const int bid = blockIdx.x;
  const int t = bid >> 9;
  const int h0 = ((bid >> 5) & 15) * 8;
  const int w0 = (bid & 31) * 4;
  const int tid = threadIdx.x;

  const int g = tid >> 3;
  const int f4 = (tid & 7) * 4;
#pragma unroll
  for (int r = 0; r < 8; ++r) {
    const int pi = r * 32 + g;
    const int pos = pi >> 3;
    const int head = pi & 7;
    const int h = h0 + (pos >> 2);
    const int w = w0 + (pos & 3);
    const int base = (((head * T + t) * H + h) * W + w) * K;
    const int fbase = base * 3;
    float4 acc = {0.f, 0.f, 0.f, 0.f};
#pragma unroll
    for (int k = 0; k < K; ++k) {
      const int dt = flows[fbase + k * 3 + 0];
      const int dh = flows[fbase + k * 3 + 1];
      const int dw = flows[fbase + k * 3 + 2];
      const float aw = attn[base + k];
      const int tt = min(max(t + dt, 0), T - 1);
      const int hh = min(max(h + dh, 0), H - 1);
      const int ww = min(max(w + dw, 0), W - 1);
      const int mm = (tt * H + hh) * W + ww;
      const ushort4 r4 = *(const ushort4*)(v + (size_t)mm * C + head * F + f4);
      acc.x += aw * bf2f(r4.x);
      acc.y += aw * bf2f(r4.y);
      acc.z += aw * bf2f(r4.z);
      acc.w += aw * bf2f(r4.w);
    }
    *(float4*)&Agg[pos][head * F + f4] = acc;
  }
  __syncthreads();

  const int tx = tid & 31;
  const int ty = tid >> 5;
  float acc2[4][8];
  {
    const float4 b0 = *(const float4*)(proj_b + tx * 8);
    const float4 b1 = *(const float4*)(proj_b + tx * 8 + 4);
#pragma unroll
    for (int i = 0; i < 4; ++i) {
      acc2[i][0] = b0.x; acc2[i][1] = b0.y; acc2[i][2] = b0.z; acc2[i][3] = b0.w;
      acc2[i][4] = b1.x; acc2[i][5] = b1.y; acc2[i][6] = b1.z; acc2[i][7] = b1.w;
    }
  }
  for (int k0 = 0; k0 < C; k0 += 32) {
#pragma unroll
    for (int i = 0; i < 8; ++i) {
      const float4 w4 = *(const float4*)(proj_w + (size_t)tid * C + k0 + i * 4);
      Bs[i * 4 + 0][tid] = w4.x;
      Bs[i * 4 + 1][tid] = w4.y;
      Bs[i * 4 + 2][tid] = w4.z;
      Bs[i * 4 + 3][tid] = w4.w;
    }
    __syncthreads();
#pragma unroll 4
    for (int kk = 0; kk < 32; ++kk) {
      const float4 bb0 = *(const float4*)&Bs[kk][tx * 8];
      const float4 bb1 = *(const float4*)&Bs[kk][tx * 8 + 4];
      float a[4];
#pragma unroll
      for (int i = 0; i < 4; ++i) a[i] = Agg[ty * 4 + i][k0 + kk];
#pragma unroll
      for (int i = 0; i < 4; ++i) {
        acc2[i][0] += a[i] * bb0.x;
        acc2[i][1] += a[i] * bb0.y;
        acc2[i][2] += a[i] * bb0.z;
        acc2[i][3] += a[i] * bb0.w;
        acc2[i][4] += a[i] * bb1.x;
        acc2[i][5] += a[i] * bb1.y;
        acc2[i][6] += a[i] * bb1.z;
        acc2[i][7] += a[i] * bb1.w;
      }
    }
    __syncthreads();
  }
#pragma unroll
  for (int i = 0; i < 4; ++i) {
    const int pos = ty * 4 + i;
    const int h = h0 + (pos >> 2);
    const int w = w0 + (pos & 3);
    const int m = (t * H + h) * W + w;
    float4 o0, o1;
    o0.x = acc2[i][0]; o0.y = acc2[i][1]; o0.z = acc2[i][2]; o0.w = acc2[i][3];
    o1.x = acc2[i][4]; o1.y = acc2[i][5]; o1.z = acc2[i][6]; o1.w = acc2[i][7];
    *(float4*)(out + (size_t)m * C + tx * 8) = o0;
    *(float4*)(out + (size_t)m * C + tx * 8 + 4) = o1;
  }
}

}  // namespace

extern "C" void kernel_launch(void* const* d_in, const int* in_sizes, int n_in,
                              void* d_out, int out_size, void* d_ws,
                              size_t ws_size, hipStream_t stream) {
  const float* x = (const float*)d_in[0];
  const float* attn = (const float*)d_in[1];
  const int* flows = (const int*)d_in[2];
  const float* v_w = (const float*)d_in[3];
  const float* proj_w = (const float*)d_in[4];
  const float* proj_b = (const float*)d_in[5];
  float* out = (float*)d_out;

  const size_t VBYTES = (size_t)M * C * 2;  // 32 MB bf16
  unsigned short* v = (unsigned short*)d_ws;

  dim3 g1(M / 128, C / 128);
  mfma_gemm<false, false><<<g1, 256, 0, stream>>>(x, v_w, v, nullptr);

  if (ws_size >= 2 * VBYTES) {
    unsigned short* agg = (unsigned short*)((char*)d_ws + VBYTES);
    gather_kernel<<<(M * HD * 4) / 256, 256, 0, stream>>>(v, attn, flows, agg);
    mfma_gemm<true, true><<<g1, 256, 0, stream>>>(agg, proj_w, out, proj_b);
  } else {
    const int nblk = T * (H / 8) * (W / 4);  // 2048
    agg_proj_kernel<<<nblk, 256, 0, stream>>>(v, attn, flows, proj_w, proj_b,
                                              out);
  }
}